// Round 7
// baseline (185.574 us; speedup 1.0000x reference)
//
#include <hip/hip_runtime.h>
#include <hip/hip_bf16.h>

#define BATCH    32768
#define HD       256
#define TMB      64
#define NTH      1024

#define SCL    2.8853900817779268f   // 2*log2(e): tanh(x) = 1 - 2/(exp2(SCL*x)+1)
#define SCLINV 0.3465735902799726f   // 1/SCL

typedef short  short8 __attribute__((ext_vector_type(8)));
typedef float  f32x4  __attribute__((ext_vector_type(4)));

// scalar f32 -> bf16 RNE (prepack only)
__device__ __forceinline__ unsigned short f2bf(float f) {
    unsigned u = __float_as_uint(f);
    return (unsigned short)((u + 0x7FFFu + ((u >> 16) & 1u)) >> 16);
}

// packed f32 pair -> bf16x2 (v_cvt_pk_bf16_f32)
__device__ __forceinline__ unsigned pk2(float a, float b) {
    __hip_bfloat162 h = __float22bfloat162_rn(make_float2(a, b));
    return *reinterpret_cast<unsigned*>(&h);
}

// ---- prepack SCL*W2^T into bf16 A-fragment order for v_mfma_f32_16x16x32_bf16 ----
// A[j][k] = SCL*W2[k][j]; lane l of tile (mt,kstep) holds A[mt*16+(l&15)][kstep*32+(l>>4)*8+i]
// stored at wsA[((mt*8 + kstep)*64 + l)*8 + i]
__global__ void prepack_w2t16(const float* __restrict__ W2, unsigned short* __restrict__ wsA) {
    const int k = blockIdx.x;        // K row of W2
    const int j = threadIdx.x;       // output column j
    const unsigned short b = f2bf(SCL * W2[k * HD + j]);
    const int mt = j >> 4, jl = j & 15;
    const int t  = k >> 5, kq = (k >> 3) & 3, i = k & 7;
    wsA[(((mt * 8) + t) * 64 + (kq * 16 + jl)) * 8 + i] = b;
}

__global__ __launch_bounds__(NTH, 4)
void cnf1d_rk4_mfma6(const float* __restrict__ z0,
                     const float* __restrict__ W1,
                     const float* __restrict__ b1,
                     const float* __restrict__ b2,
                     const float* __restrict__ W3,
                     const float* __restrict__ b3,
                     const unsigned short* __restrict__ wsA,
                     float* __restrict__ out)
{
    // staging: [granule g=feat/8][col], cols 0..63 = h1 samples, 64..127 = th1 samples
    __shared__ __align__(16) short Abuf[32 * 128 * 8];   // 64 KB
    __shared__ float4 pt[HD];                            // (SCL*w1z, SCL*w1t, SCL*b1, w1z)
    __shared__ float  b2sc[HD], w3t[HD];                 // SCL*b2, W3
    __shared__ float2 kz[16][TMB];                       // per-wave (pdz,pdd) partials
                                                         // total 79,872 B -> 1 block/CU
    const int tid  = threadIdx.x;
    const int s0   = blockIdx.x * TMB;
    const int lane = tid & 63;
    const int l15  = lane & 15;
    const int lq   = lane >> 4;       // 0..3
    const int w    = tid >> 6;        // wave 0..15: owns j-tile [w*16, w*16+16)
    const int so   = tid & 63;        // owned sample (phase 1/4)

    if (tid < HD) {
        const float w0 = W1[tid];
        pt[tid]   = make_float4(SCL * w0, SCL * W1[HD + tid], SCL * b1[tid], w0);
        b2sc[tid] = SCL * b2[tid];
        w3t[tid]  = W3[tid];
    }

    // loop-invariant register tiles
    const short8* __restrict__ wsA8 = (const short8*)wsA;
    short8 w2f[8];
    #pragma unroll
    for (int ks = 0; ks < 8; ++ks)
        w2f[ks] = wsA8[(w * 8 + ks) * 64 + lane];

    float zbr = z0[s0 + so];
    float zcr = zbr, skzr = 0.f, skdr = 0.f, daccr = 0.f;
    __syncthreads();

    // per-lane j-column constants (j = w*16 + lq*4 + r)
    const int j4 = w * 16 + lq * 4;
    const float4 w3v = *(const float4*)&w3t[j4];
    const float4 b2v = *(const float4*)&b2sc[j4];
    const f32x4  binit = { b2v.x, b2v.y, b2v.z, b2v.w };

    const float dt  = 0.25f;
    const float b3v = b3[0];
    uint4* __restrict__ Ab4 = (uint4*)Abuf;
    const short8* __restrict__ Ab8 = (const short8*)Abuf;

    for (int it = 0; it < 16; ++it) {
        const int e    = it & 3;
        const int step = it >> 2;
        const float te = step * dt + ((e == 0) ? 0.f : ((e == 3) ? dt : 0.5f * dt));

        // ---- phase 1: feats [w*16, w*16+16) of sample `so` -> staged bf16 ----
        #pragma unroll
        for (int g2 = 0; g2 < 2; ++g2) {
            const int j0 = w * 16 + g2 * 8;      // wave-uniform
            float h[8], th[8];
            #pragma unroll
            for (int ee = 0; ee < 8; ++ee) {
                const float4 p = pt[j0 + ee];
                const float a  = fmaf(zcr, p.x, fmaf(te, p.y, p.z));
                const float ev = __builtin_amdgcn_exp2f(a);
                const float r1 = __builtin_amdgcn_rcpf(ev + 1.0f);
                const float hh = fmaf(-2.f, r1, 1.f);
                h[ee]  = hh;
                th[ee] = (1.f - hh * hh) * p.w;
            }
            uint4 vU, vT;
            vU.x = pk2(h[0], h[1]);   vU.y = pk2(h[2], h[3]);
            vU.z = pk2(h[4], h[5]);   vU.w = pk2(h[6], h[7]);
            vT.x = pk2(th[0], th[1]); vT.y = pk2(th[2], th[3]);
            vT.z = pk2(th[4], th[5]); vT.w = pk2(th[6], th[7]);
            const int gr = w * 2 + g2;
            Ab4[gr * 128 + so]      = vU;
            Ab4[gr * 128 + 64 + so] = vT;
        }
        __syncthreads();

        // ---- phase 2: both sample-groups' MFMA, then both epilogues (no barrier
        //      inside: scheduler overlaps epi-A VALU with group-B MFMA) ----
        f32x4 aU0 = binit, aU1 = binit, aT0 = {0,0,0,0}, aT1 = {0,0,0,0};  // group A
        f32x4 bU0 = binit, bU1 = binit, bT0 = {0,0,0,0}, bT1 = {0,0,0,0};  // group B

        #pragma unroll
        for (int ks = 0; ks < 8; ++ks) {
            const int base = (ks * 4 + lq) * 128 + l15;
            const short8 aW = w2f[ks];
            aU0 = __builtin_amdgcn_mfma_f32_16x16x32_bf16(aW, Ab8[base +   0], aU0, 0, 0, 0);
            aU1 = __builtin_amdgcn_mfma_f32_16x16x32_bf16(aW, Ab8[base +  16], aU1, 0, 0, 0);
            aT0 = __builtin_amdgcn_mfma_f32_16x16x32_bf16(aW, Ab8[base +  64], aT0, 0, 0, 0);
            aT1 = __builtin_amdgcn_mfma_f32_16x16x32_bf16(aW, Ab8[base +  80], aT1, 0, 0, 0);
        }
        #pragma unroll
        for (int ks = 0; ks < 8; ++ks) {
            const int base = (ks * 4 + lq) * 128 + l15;
            const short8 aW = w2f[ks];
            bU0 = __builtin_amdgcn_mfma_f32_16x16x32_bf16(aW, Ab8[base +  32], bU0, 0, 0, 0);
            bU1 = __builtin_amdgcn_mfma_f32_16x16x32_bf16(aW, Ab8[base +  48], bU1, 0, 0, 0);
            bT0 = __builtin_amdgcn_mfma_f32_16x16x32_bf16(aW, Ab8[base +  96], bT0, 0, 0, 0);
            bT1 = __builtin_amdgcn_mfma_f32_16x16x32_bf16(aW, Ab8[base + 112], bT1, 0, 0, 0);
        }

        // ---- phase 3: epilogues. D-layout: col=lane&15 (sample), row=lq*4+r (j) ----
        #pragma unroll
        for (int G = 0; G < 2; ++G) {
            #pragma unroll
            for (int t = 0; t < 2; ++t) {
                const f32x4 U = G ? (t ? bU1 : bU0) : (t ? aU1 : aU0);
                const f32x4 T = G ? (t ? bT1 : bT0) : (t ? aT1 : aT0);
                float pz = 0.f, pd = 0.f;
                #pragma unroll
                for (int r = 0; r < 4; ++r) {
                    const float ev  = __builtin_amdgcn_exp2f(U[r]);    // SCL*(u+b2)
                    const float r1  = __builtin_amdgcn_rcpf(ev + 1.0f);
                    const float h2  = fmaf(-2.f, r1, 1.f);
                    const float th2 = fmaf(-h2 * h2, T[r], T[r]);      // (1-h2^2)*SCL*tu
                    const float w3c = ((const float*)&w3v)[r];
                    pz = fmaf(h2,  w3c, pz);
                    pd = fmaf(th2, w3c, pd);
                }
                pd *= SCLINV;
                pz += __shfl_xor(pz, 16);  pz += __shfl_xor(pz, 32);   // sum 16 j
                pd += __shfl_xor(pd, 16);  pd += __shfl_xor(pd, 32);
                if (lq == 0) kz[w][G * 32 + t * 16 + l15] = make_float2(pz, pd);
            }
        }
        __syncthreads();

        // ---- phase 4: RK4 update (per-thread, redundant per sample) ----
        {
            float k_z = b3v, k_d = 0.f;
            #pragma unroll
            for (int wv = 0; wv < 16; ++wv) {
                const float2 a = kz[wv][so];
                k_z += a.x; k_d += a.y;
            }
            const float cw = (e == 1 || e == 2) ? 2.f : 1.f;
            skzr += cw * k_z;
            skdr += cw * k_d;
            if (e < 3) {
                zcr = fmaf((e == 2) ? dt : 0.5f * dt, k_z, zbr);
            } else {
                zbr   = fmaf(dt / 6.f, skzr, zbr);
                zcr   = zbr;
                daccr = fmaf(dt / 6.f, skdr, daccr);
                skzr = 0.f; skdr = 0.f;
            }
        }
    }

    if (tid < TMB) {
        out[s0 + tid]         = zbr;     // zf
        out[BATCH + s0 + tid] = daccr;   // div_int
    }
}

extern "C" void kernel_launch(void* const* d_in, const int* in_sizes, int n_in,
                              void* d_out, int out_size, void* d_ws, size_t ws_size,
                              hipStream_t stream) {
    const float* z0 = (const float*)d_in[0];
    const float* W1 = (const float*)d_in[1];
    const float* b1 = (const float*)d_in[2];
    const float* W2 = (const float*)d_in[3];
    const float* b2 = (const float*)d_in[4];
    const float* W3 = (const float*)d_in[5];
    const float* b3 = (const float*)d_in[6];
    float* out = (float*)d_out;
    unsigned short* wsA = (unsigned short*)d_ws;   // 128 KB bf16 A-frag SCL*W2^T

    hipLaunchKernelGGL(prepack_w2t16, dim3(HD), dim3(HD), 0, stream, W2, wsA);
    hipLaunchKernelGGL(cnf1d_rk4_mfma6, dim3(BATCH / TMB), dim3(NTH), 0, stream,
                       z0, W1, b1, b2, W3, b3, wsA, out);
}

// Round 8
// 165.543 us; speedup vs baseline: 1.1210x; 1.1210x over previous
//
#include <hip/hip_runtime.h>
#include <hip/hip_bf16.h>

#define BATCH    32768
#define HD       256
#define TM       32
#define NTHREADS 512

#define SCL    2.8853900817779268f   // 2*log2(e): tanh(x) = 1 - 2/(exp2(SCL*x)+1)
#define SCLINV 0.3465735902799726f   // 1/SCL

typedef short  short8 __attribute__((ext_vector_type(8)));
typedef float  f32x16 __attribute__((ext_vector_type(16)));
typedef float  f32x2  __attribute__((ext_vector_type(2)));

// scalar f32 -> bf16 RNE (prepack only)
__device__ __forceinline__ unsigned short f2bf(float f) {
    unsigned u = __float_as_uint(f);
    return (unsigned short)((u + 0x7FFFu + ((u >> 16) & 1u)) >> 16);
}

// packed f32 pair -> bf16x2 (v_cvt_pk_bf16_f32)
__device__ __forceinline__ unsigned pk2(float a, float b) {
    __hip_bfloat162 h = __float22bfloat162_rn(make_float2(a, b));
    return *reinterpret_cast<unsigned*>(&h);
}

// ---- prepack W2^T (scaled by SCL) into bf16 MFMA A-fragment order ----
// A-frag for v_mfma_f32_32x32x16_bf16: lane l holds A[mt*32 + (l&31)][kstep*16 + (l>>5)*8 + i]
// where A = SCL * W2^T. chunk (mt, kstep) at ((mt*16 + kstep)*64 + lane)*8 + i
__global__ void prepack_w2t(const float* __restrict__ W2, unsigned short* __restrict__ wsA) {
    const int k = blockIdx.x;        // K row of W2
    const int j = threadIdx.x;       // output column j (row of W2^T)
    const unsigned short b = f2bf(SCL * W2[k * HD + j]);
    const int kstep = k >> 4, kl = k & 15, hi2 = kl >> 3, i = kl & 7;
    const int mt = j >> 5, jl = j & 31;
    wsA[(((mt * 16) + kstep) * 64 + (hi2 * 32 + jl)) * 8 + i] = b;
}

__global__ __launch_bounds__(NTHREADS, 4)
void cnf1d_rk4_mfma7(const float* __restrict__ z0,
                     const float* __restrict__ W1,
                     const float* __restrict__ b1,
                     const float* __restrict__ b2,
                     const float* __restrict__ W3,
                     const float* __restrict__ b3,
                     const unsigned short* __restrict__ wsA,
                     float* __restrict__ out)
{
    // B staging: [h1^T cols 0..31 ; th1^T cols 32..63], bf16, blocked:
    // 16B slot (kgranule g = k/8, row) at uint4 index g*64 + row
    __shared__ __align__(16) short Abuf[64 * 256];    // 32 KB
    __shared__ float w1zS[HD], w1tS[HD], b1S[HD], w0S[HD];   // SoA params, 4 KB
    __shared__ float b2sc[HD], w3t[HD];               // SCL*b2, W3   2 KB
    __shared__ float2 kz[8][TM];                      // per-wave (pdz,pdd) 2 KB
                                                      // total 40,960 B
    const int tid  = threadIdx.x;
    const int s0   = blockIdx.x * TM;
    const int lane = tid & 63;
    const int ln31 = lane & 31;
    const int hi   = lane >> 5;
    const int wid  = tid >> 6;        // wave id 0..7: owns j in [wid*32, wid*32+32)
    const int s    = tid & 31;        // owned sample
    const int fb   = tid >> 5;        // phase-1 feature block 0..15 (16 features)

    if (tid < HD) {
        const float w0 = W1[tid];
        w1zS[tid] = SCL * w0;
        w1tS[tid] = SCL * W1[HD + tid];
        b1S[tid]  = SCL * b1[tid];
        w0S[tid]  = w0;
        b2sc[tid] = SCL * b2[tid];
        w3t[tid]  = W3[tid];
    }

    // ---- loop-invariant: this wave's W2^T fragments, in registers (64 VGPR) ----
    const short8* __restrict__ wsA8 = (const short8*)wsA;
    short8 w2f[16];
    #pragma unroll
    for (int kk = 0; kk < 16; ++kk)
        w2f[kk] = wsA8[(wid * 16 + kk) * 64 + lane];

    float zbr = z0[s0 + s];
    float zcr = zbr, skzr = 0.f, skdr = 0.f, daccr = 0.f;
    __syncthreads();

    const float dt  = 0.25f;
    const float b3v = b3[0];
    uint4* __restrict__ Ab4 = (uint4*)Abuf;
    const short8* __restrict__ Ab8 = (const short8*)Abuf;
    const int jb = wid * 32 + hi * 4;
    const f32x2 one2 = {1.f, 1.f};
    const f32x2 m2   = {-2.f, -2.f};

    for (int it = 0; it < 16; ++it) {
        const int e    = it & 3;
        const int step = it >> 2;
        const float te = step * dt + ((e == 0) ? 0.f : ((e == 3) ? dt : 0.5f * dt));

        // ---- phase 1: h1/th1 (16 features/thread), packed-f32 pairs ----
        {
            const f32x2 zc2 = {zcr, zcr};
            const f32x2 te2 = {te, te};
            #pragma unroll
            for (int g2 = 0; g2 < 2; ++g2) {
                const int j0 = fb * 16 + g2 * 8;
                const float4 wzA = *(const float4*)&w1zS[j0];
                const float4 wzB = *(const float4*)&w1zS[j0 + 4];
                const float4 wtA = *(const float4*)&w1tS[j0];
                const float4 wtB = *(const float4*)&w1tS[j0 + 4];
                const float4 bbA = *(const float4*)&b1S[j0];
                const float4 bbB = *(const float4*)&b1S[j0 + 4];
                const float4 w0A = *(const float4*)&w0S[j0];
                const float4 w0B = *(const float4*)&w0S[j0 + 4];
                const f32x2 wz[4] = {{wzA.x, wzA.y}, {wzA.z, wzA.w}, {wzB.x, wzB.y}, {wzB.z, wzB.w}};
                const f32x2 wt[4] = {{wtA.x, wtA.y}, {wtA.z, wtA.w}, {wtB.x, wtB.y}, {wtB.z, wtB.w}};
                const f32x2 bb[4] = {{bbA.x, bbA.y}, {bbA.z, bbA.w}, {bbB.x, bbB.y}, {bbB.z, bbB.w}};
                const f32x2 w0p[4] = {{w0A.x, w0A.y}, {w0A.z, w0A.w}, {w0B.x, w0B.y}, {w0B.z, w0B.w}};
                f32x2 hh[4], th[4];
                #pragma unroll
                for (int pp = 0; pp < 4; ++pp) {
                    const f32x2 a = __builtin_elementwise_fma(zc2, wz[pp],
                                      __builtin_elementwise_fma(te2, wt[pp], bb[pp]));
                    f32x2 ev; ev.x = __builtin_amdgcn_exp2f(a.x);
                              ev.y = __builtin_amdgcn_exp2f(a.y);
                    const f32x2 e1 = ev + one2;                       // v_pk_add_f32
                    f32x2 rv; rv.x = __builtin_amdgcn_rcpf(e1.x);
                              rv.y = __builtin_amdgcn_rcpf(e1.y);
                    const f32x2 h = __builtin_elementwise_fma(m2, rv, one2);   // tanh pair
                    const f32x2 t1 = __builtin_elementwise_fma(-h, h, one2);   // 1 - h^2
                    hh[pp] = h;
                    th[pp] = t1 * w0p[pp];                            // v_pk_mul_f32
                }
                uint4 vU, vT;
                vU.x = pk2(hh[0].x, hh[0].y);  vU.y = pk2(hh[1].x, hh[1].y);
                vU.z = pk2(hh[2].x, hh[2].y);  vU.w = pk2(hh[3].x, hh[3].y);
                vT.x = pk2(th[0].x, th[0].y);  vT.y = pk2(th[1].x, th[1].y);
                vT.z = pk2(th[2].x, th[2].y);  vT.w = pk2(th[3].x, th[3].y);
                const int gr = j0 >> 3;
                Ab4[gr * 64 + s]      = vU;   // U col s
                Ab4[gr * 64 + 32 + s] = vT;   // T col 32+s
            }
        }
        __syncthreads();

        // ---- phase 2: acc = SCL*(W2^T[j-tile] @ [h1;th1]^T) + SCL*b2 ----
        f32x16 accU, accT;
        #pragma unroll
        for (int rq = 0; rq < 4; ++rq) {
            const float4 bq = *(const float4*)&b2sc[jb + rq * 8];
            accU[rq * 4 + 0] = bq.x;  accU[rq * 4 + 1] = bq.y;
            accU[rq * 4 + 2] = bq.z;  accU[rq * 4 + 3] = bq.w;
            accT[rq * 4 + 0] = 0.f;   accT[rq * 4 + 1] = 0.f;
            accT[rq * 4 + 2] = 0.f;   accT[rq * 4 + 3] = 0.f;
        }

        #pragma unroll
        for (int kk = 0; kk < 16; ++kk) {
            const short8 hU = Ab8[(kk * 2 + hi) * 64 + ln31];
            const short8 hT = Ab8[(kk * 2 + hi) * 64 + 32 + ln31];
            accU = __builtin_amdgcn_mfma_f32_32x32x16_bf16(w2f[kk], hU, accU, 0, 0, 0);
            accT = __builtin_amdgcn_mfma_f32_32x32x16_bf16(w2f[kk], hT, accT, 0, 0, 0);
        }

        // ---- phase 3: epilogue, packed pairs; j-reduction in-lane (lane = sample) ----
        f32x2 pz2 = {0.f, 0.f}, pd2 = {0.f, 0.f};
        #pragma unroll
        for (int rq = 0; rq < 4; ++rq) {
            const float4 w3q = *(const float4*)&w3t[jb + rq * 8];
            const f32x2 w3p[2] = {{w3q.x, w3q.y}, {w3q.z, w3q.w}};
            #pragma unroll
            for (int pr = 0; pr < 2; ++pr) {
                const int r = rq * 4 + pr * 2;
                const f32x2 u2 = {accU[r], accU[r + 1]};              // SCL*(u+b2)
                const f32x2 t2 = {accT[r], accT[r + 1]};              // SCL*tu
                f32x2 ev; ev.x = __builtin_amdgcn_exp2f(u2.x);
                          ev.y = __builtin_amdgcn_exp2f(u2.y);
                const f32x2 e1 = ev + one2;
                f32x2 rv; rv.x = __builtin_amdgcn_rcpf(e1.x);
                          rv.y = __builtin_amdgcn_rcpf(e1.y);
                const f32x2 h2 = __builtin_elementwise_fma(m2, rv, one2);
                const f32x2 hq = h2 * h2;
                const f32x2 th2 = __builtin_elementwise_fma(-hq, t2, t2);  // (1-h2^2)*SCL*tu
                pz2 = __builtin_elementwise_fma(h2,  w3p[pr], pz2);
                pd2 = __builtin_elementwise_fma(th2, w3p[pr], pd2);
            }
        }
        float pdz = pz2.x + pz2.y;
        float pdd = (pd2.x + pd2.y) * SCLINV;        // undo tangent scale once
        pdz += __shfl_xor(pdz, 32);                  // combine hi halves (j += 4 rows)
        pdd += __shfl_xor(pdd, 32);
        if (hi == 0) kz[wid][ln31] = make_float2(pdz, pdd);
        __syncthreads();

        // ---- phase 4: RK4 update (registers, redundant across threads of a sample) ----
        {
            float k_z = b3v, k_d = 0.f;
            #pragma unroll
            for (int w = 0; w < 8; ++w) {
                const float2 a = kz[w][s];
                k_z += a.x; k_d += a.y;
            }
            const float cw = (e == 1 || e == 2) ? 2.f : 1.f;
            skzr += cw * k_z;
            skdr += cw * k_d;
            if (e < 3) {
                zcr = fmaf((e == 2) ? dt : 0.5f * dt, k_z, zbr);
            } else {
                zbr   = fmaf(dt / 6.f, skzr, zbr);
                zcr   = zbr;
                daccr = fmaf(dt / 6.f, skdr, daccr);
                skzr = 0.f; skdr = 0.f;
            }
        }
    }

    if (tid < TM) {
        out[s0 + tid]         = zbr;     // zf
        out[BATCH + s0 + tid] = daccr;   // div_int
    }
}

extern "C" void kernel_launch(void* const* d_in, const int* in_sizes, int n_in,
                              void* d_out, int out_size, void* d_ws, size_t ws_size,
                              hipStream_t stream) {
    const float* z0 = (const float*)d_in[0];
    const float* W1 = (const float*)d_in[1];
    const float* b1 = (const float*)d_in[2];
    const float* W2 = (const float*)d_in[3];
    const float* b2 = (const float*)d_in[4];
    const float* W3 = (const float*)d_in[5];
    const float* b3 = (const float*)d_in[6];
    float* out = (float*)d_out;
    unsigned short* wsA = (unsigned short*)d_ws;   // 128 KB bf16 A-frag SCL*W2^T

    hipLaunchKernelGGL(prepack_w2t, dim3(HD), dim3(HD), 0, stream, W2, wsA);
    hipLaunchKernelGGL(cnf1d_rk4_mfma7, dim3(BATCH / TM), dim3(NTHREADS), 0, stream,
                       z0, W1, b1, b2, W3, b3, wsA, out);
}